// Round 4
// baseline (359.471 us; speedup 1.0000x reference)
//
#include <hip/hip_runtime.h>

// Problem constants
#define B_   32
#define H_   64
#define W_   64
#define CIN  128
#define F_   256
#define K_   1152          // 3*3*128
#define M_   4096          // H*W per batch

#define WBT_BYTES ((size_t)B_ * F_ * K_ * 2)   // 18,874,368
#define ZPAGE_OFF WBT_BYTES                    // 256B zero page after WbT

typedef __attribute__((ext_vector_type(8))) short bf16x8;
typedef __attribute__((ext_vector_type(4))) float f32x4;

// pack two floats -> two bf16 (round-to-nearest) in one v_perm
__device__ __forceinline__ unsigned pkbf(float a, float b) {
    unsigned ua = __builtin_bit_cast(unsigned, a) + 0x8000u;
    unsigned ub = __builtin_bit_cast(unsigned, b) + 0x8000u;
    return __builtin_amdgcn_perm(ub, ua, 0x07060302u);
}

// ---------------------------------------------------------------------------
// Kernel B: WbT[b][f][k] = bf16( W[k][f] * Werr[b][k][f] ), vectorized.
// tile 32k x 64f per block; float4 global loads; b128 global stores.
// grid = 32 * 36 * 4 = 4608 blocks, 256 threads.
// ---------------------------------------------------------------------------
__global__ void wbt_kernel(const float* __restrict__ W,
                           const float* __restrict__ Werr,
                           unsigned short* __restrict__ WbT,
                           unsigned int* __restrict__ zpage) {
    __shared__ float tile[32 * 68];
    int bid = blockIdx.x;
    int ft   = bid & 3;
    int rest = bid >> 2;
    int kt   = rest % 36;
    int b    = rest / 36;
    int k0 = kt * 32;
    int f0 = ft * 64;
    int t  = threadIdx.x;

    if (bid == 0 && t < 64) zpage[t] = 0u;   // 256B zero page, every call

    #pragma unroll
    for (int i = 0; i < 2; ++i) {
        int c   = i * 256 + t;
        int kl  = c >> 4;
        int fl4 = c & 15;
        size_t src = (size_t)(k0 + kl) * F_ + f0 + fl4 * 4;
        f32x4 w4 = *(const f32x4*)&W[src];
        f32x4 e4 = *(const f32x4*)&Werr[(size_t)b * (K_ * F_) + src];
        f32x4 v  = w4 * e4;
        *(f32x4*)&tile[kl * 68 + fl4 * 4] = v;
    }
    __syncthreads();
    {
        int c  = t;
        int fl = c >> 2;
        int ku = c & 3;
        unsigned pk[4];
        #pragma unroll
        for (int j2 = 0; j2 < 4; ++j2) {
            float x0 = tile[(ku * 8 + j2 * 2 + 0) * 68 + fl];
            float x1 = tile[(ku * 8 + j2 * 2 + 1) * 68 + fl];
            pk[j2] = pkbf(x0, x1);
        }
        size_t dst = ((size_t)(b * F_ + f0 + fl)) * K_ + k0 + ku * 8;
        *(uint4*)&WbT[dst] = make_uint4(pk[0], pk[1], pk[2], pk[3]);
    }
}

// ---------------------------------------------------------------------------
// Kernel C: implicit-im2col GEMM, fully register-pipelined staging.
// Tile 256(M) x 128(N), BK=32, 36 K-steps. 512 threads = 8 waves (4m x 2n),
// wave tile 64x64 via 4x4 grid of 16x16x32 MFMA.
// A: fp32 X -> regs (prefetch kt+1 during kt's MFMA) -> cvt bf16 -> ds_write.
// B: bf16 WbT -> regs (same pipeline) -> ds_write.  NO global_load_lds, so
//    the barrier's vmcnt(0) drain never waits on in-flight global loads.
// LDS: XOR swizzle (phys 16B unit = logical ^ ((row>>1)&3)) -> write 2-way
//    (free), read at the 8-phase ds_read_b128 floor.
// grid = 32b * 16mt * 2nt = 1024, XCD-swizzled by (b,nt) group.
// ---------------------------------------------------------------------------
__global__ __launch_bounds__(512, 4)
void gemm_kernel(const float* __restrict__ X,
                 const unsigned short* __restrict__ WbT,
                 const float* __restrict__ zpage,
                 const float* __restrict__ bias,
                 const float* __restrict__ Berr,
                 float* __restrict__ Out) {
    __shared__ unsigned short As[256 * 32];   // 16KB
    __shared__ unsigned short Bs[128 * 32];   //  8KB

    int bid = blockIdx.x;
    // XCD swizzle: 16 mt-blocks of one (b,nt) group share an XCD (bid%8 const)
    int g   = (bid & 7) | ((bid >> 7) << 3);   // 0..63
    int mt  = (bid >> 3) & 15;
    int b   = g >> 1;
    int nt  = g & 1;
    int pm0 = mt * 256;

    int t    = threadIdx.x;
    int lane = t & 63;
    int wv   = t >> 6;          // 0..7
    int wm   = wv >> 1;         // 0..3
    int wn   = wv & 1;          // 0..1
    int l16  = lane & 15;
    int quad = lane >> 4;
    int sx   = (l16 >> 1) & 3;  // read-side swizzle key

    // ---- A staging state: one half-pixel (16 channels) per thread ----
    int ml   = t >> 1;          // 0..255
    int half = t & 1;
    int m    = pm0 + ml;
    int hb   = m >> 6;          // 0..63
    int wwv  = m & 63;
    const float* Abase = X + (((size_t)b * 64 + hb - 1) * 64 + (wwv - 1)) * 128
                           + half * 16;
    unsigned vm = 0;
    #pragma unroll
    for (int khw = 0; khw < 9; ++khw) {
        int kh = (khw * 11) >> 5;
        int kw = khw - kh * 3;
        bool ok = ((unsigned)(hb + kh - 1) < 64u) && ((unsigned)(wwv + kw - 1) < 64u);
        vm |= (unsigned)ok << khw;
    }
    int sA    = (ml >> 1) & 3;
    int ldsA0 = ml * 32 + (((half * 2)     ^ sA) * 8);
    int ldsA1 = ml * 32 + (((half * 2 + 1) ^ sA) * 8);

    // ---- B staging state: one 16B chunk per thread ----
    const unsigned short* wb = WbT + ((size_t)(b * F_ + nt * 128)) * K_;
    int nl  = t >> 2;           // 0..127
    int off = t & 3;
    const unsigned short* Bgl = wb + (size_t)nl * K_ + (off ^ ((nl >> 1) & 3)) * 8;
    int ldsB = nl * 32 + off * 8;

    // ---- fragment read offsets (kt-invariant) ----
    int aoff[4], boff[4];
    #pragma unroll
    for (int i = 0; i < 4; ++i) {
        aoff[i] = (wm * 64 + i * 16 + l16) * 32 + ((quad ^ sx) * 8);
        boff[i] = (wn * 64 + i * 16 + l16) * 32 + ((quad ^ sx) * 8);
    }

    f32x4 acc[4][4];
    #pragma unroll
    for (int mi = 0; mi < 4; ++mi)
        #pragma unroll
        for (int ni = 0; ni < 4; ++ni)
            acc[mi][ni] = (f32x4){0.f, 0.f, 0.f, 0.f};

    // ---- prefetch kt=0 ----
    f32x4 pr0, pr1, pr2, pr3;
    {
        const float* p = (vm & 1) ? Abase : zpage;
        pr0 = *(const f32x4*)(p);
        pr1 = *(const f32x4*)(p + 4);
        pr2 = *(const f32x4*)(p + 8);
        pr3 = *(const f32x4*)(p + 12);
    }
    uint4 breg = *(const uint4*)Bgl;

    for (int kt = 0; kt < 36; ++kt) {
        // cvt prefetched A (regs only)
        uint4 lo, hi;
        lo.x = pkbf(pr0[0], pr0[1]);  lo.y = pkbf(pr0[2], pr0[3]);
        lo.z = pkbf(pr1[0], pr1[1]);  lo.w = pkbf(pr1[2], pr1[3]);
        hi.x = pkbf(pr2[0], pr2[1]);  hi.y = pkbf(pr2[2], pr2[3]);
        hi.z = pkbf(pr3[0], pr3[1]);  hi.w = pkbf(pr3[2], pr3[3]);

        if (kt) __syncthreads();           // readers of kt-1 done
        *(uint4*)&As[ldsA0] = lo;
        *(uint4*)&As[ldsA1] = hi;
        *(uint4*)&Bs[ldsB]  = breg;
        __syncthreads();                   // staging visible (lgkm only)

        // prefetch kt+1; drains at next iteration's cvt / ds_write (use),
        // a full MFMA-section away — never at a barrier.
        if (kt < 35) {
            int ktn  = kt + 1;
            int khw  = ktn >> 2;
            int kh   = (khw * 11) >> 5;
            int kw   = khw - kh * 3;
            int koff = kh * 8192 + kw * 128 + ((ktn & 3) << 5);
            const float* p = ((vm >> khw) & 1) ? Abase + koff : zpage;
            pr0 = *(const f32x4*)(p);
            pr1 = *(const f32x4*)(p + 4);
            pr2 = *(const f32x4*)(p + 8);
            pr3 = *(const f32x4*)(p + 12);
            breg = *(const uint4*)(Bgl + ktn * 32);
        }

        bf16x8 af[4], bf[4];
        #pragma unroll
        for (int i = 0; i < 4; ++i) {
            af[i] = *(const bf16x8*)&As[aoff[i]];
            bf[i] = *(const bf16x8*)&Bs[boff[i]];
        }
        #pragma unroll
        for (int mi = 0; mi < 4; ++mi)
            #pragma unroll
            for (int ni = 0; ni < 4; ++ni)
                acc[mi][ni] = __builtin_amdgcn_mfma_f32_16x16x32_bf16(
                    af[mi], bf[ni], acc[mi][ni], 0, 0, 0);
    }

    // ---- epilogue: + bias*Berr, ReLU, store fp32 ----
    float mb[4];
    #pragma unroll
    for (int ni = 0; ni < 4; ++ni) {
        int f = nt * 128 + wn * 64 + ni * 16 + l16;
        mb[ni] = bias[f] * Berr[b * F_ + f];
    }
    #pragma unroll
    for (int mi = 0; mi < 4; ++mi) {
        #pragma unroll
        for (int rr = 0; rr < 4; ++rr) {
            int mm = pm0 + wm * 64 + mi * 16 + quad * 4 + rr;
            float* orow = Out + ((size_t)b * M_ + mm) * F_ + nt * 128 + wn * 64;
            #pragma unroll
            for (int ni = 0; ni < 4; ++ni) {
                float v = acc[mi][ni][rr] + mb[ni];
                orow[ni * 16 + l16] = fmaxf(v, 0.0f);
            }
        }
    }
}

// ---------------------------------------------------------------------------
// Zero-workspace fallback: direct conv (slow but correct), ws < 19MB only.
// ---------------------------------------------------------------------------
__global__ __launch_bounds__(256)
void fallback_kernel(const float* __restrict__ X, const float* __restrict__ W,
                     const float* __restrict__ bias, const float* __restrict__ Werr,
                     const float* __restrict__ Berr, float* __restrict__ Out) {
    __shared__ float Xs[3 * 66 * 128];
    int bid = blockIdx.x;
    int b = bid >> 6;
    int h = bid & 63;
    int t = threadIdx.x;
    int f = t;

    for (int e = t; e < 3 * 66 * 128; e += 256) {
        int kh  = e / (66 * 128);
        int rem = e - kh * 66 * 128;
        int w66 = rem >> 7;
        int c   = rem & 127;
        int hh = h + kh - 1, ww = w66 - 1;
        float v = 0.f;
        if (hh >= 0 && hh < 64 && ww >= 0 && ww < 64)
            v = X[(((size_t)b * 64 + hh) * 64 + ww) * 128 + c];
        Xs[e] = v;
    }
    __syncthreads();

    float acc[64];
    #pragma unroll
    for (int w = 0; w < 64; ++w) acc[w] = 0.f;

    for (int kk = 0; kk < 9; ++kk) {
        int kh = (kk * 11) >> 5;
        int kw = kk - kh * 3;
        for (int c = 0; c < 128; ++c) {
            size_t wi = ((size_t)kk * 128 + c) * 256 + f;
            float wvv = W[wi] * Werr[(size_t)b * (K_ * F_) + wi];
            const float* xr = &Xs[(kh * 66 + kw) * 128 + c];
            #pragma unroll
            for (int w = 0; w < 64; ++w)
                acc[w] = fmaf(xr[w * 128], wvv, acc[w]);
        }
    }
    float mb = bias[f] * Berr[b * 256 + f];
    for (int w = 0; w < 64; ++w)
        Out[(((size_t)b * 64 + h) * 64 + w) * 256 + f] = fmaxf(acc[w] + mb, 0.f);
}

// ---------------------------------------------------------------------------
extern "C" void kernel_launch(void* const* d_in, const int* in_sizes, int n_in,
                              void* d_out, int out_size, void* d_ws, size_t ws_size,
                              hipStream_t stream) {
    const float* X    = (const float*)d_in[0];
    const float* W    = (const float*)d_in[1];
    const float* bias = (const float*)d_in[2];
    const float* Werr = (const float*)d_in[3];
    const float* Berr = (const float*)d_in[4];
    float* Out = (float*)d_out;

    if (ws_size >= WBT_BYTES + 256) {
        unsigned short* WbT  = (unsigned short*)d_ws;
        unsigned int*   zpg  = (unsigned int*)((char*)d_ws + ZPAGE_OFF);
        wbt_kernel<<<B_ * 36 * 4, 256, 0, stream>>>(W, Werr, WbT, zpg);
        gemm_kernel<<<B_ * 16 * 2, 512, 0, stream>>>(X, WbT, (const float*)zpg,
                                                     bias, Berr, Out);
    } else {
        fallback_kernel<<<B_ * 64, 256, 0, stream>>>(X, W, bias, Werr, Berr, Out);
    }
}